// Round 1
// baseline (794.495 us; speedup 1.0000x reference)
//
#include <hip/hip_runtime.h>
#include <math.h>

#define C 320
#define NPTS 2048
#define SUPPTS 20480   // 2*5*2048 support points
#define QPTS 4096      // 2*2048 query points
#define KP 100         // prototypes per problem
#define JT 20          // proto tile size
#define NCLS 3

// ---------------- kernel 1: reciprocal norms ----------------
__global__ __launch_bounds__(256) void k_rnorm(const float* __restrict__ sup,
                                               const float* __restrict__ qry,
                                               float* __restrict__ srn,
                                               float* __restrict__ qrn) {
    int i = blockIdx.x * 256 + threadIdx.x;   // 0..24575
    if (i < SUPPTS) {
        int ws = i >> 11, n = i & 2047;
        const float* base = sup + ((size_t)ws * C) * NPTS + n;
        float s = 0.f;
        #pragma unroll 8
        for (int c = 0; c < C; c++) { float v = base[(size_t)c * NPTS]; s += v * v; }
        srn[i] = 1.0f / (sqrtf(s) + 1e-8f);
    } else {
        int j = i - SUPPTS;                   // 0..4095
        int q = j >> 11, n = j & 2047;
        const float* base = qry + ((size_t)q * C) * NPTS + n;
        float s = 0.f;
        #pragma unroll 8
        for (int c = 0; c < C; c++) { float v = base[(size_t)c * NPTS]; s += v * v; }
        qrn[j] = 1.0f / (sqrtf(s) + 1e-8f);
    }
}

// ---------------- kernel 2: seed selection (first 100 masked per problem) ----------------
__global__ __launch_bounds__(64) void k_seeds(const int* __restrict__ y, int* __restrict__ seed) {
    int prob = blockIdx.x;            // 0: fg way0, 1: fg way1, 2: bg (all)
    int lane = threadIdx.x;
    int M    = (prob == 2) ? SUPPTS : 10240;
    int base = (prob == 1) ? 10240 : 0;
    int found = 0;
    for (int chunk = 0; chunk < M && found < KP; chunk += 64) {
        int idx = chunk + lane;
        int yy = y[base + idx];
        int m = (prob == 2) ? (1 - yy) : yy;
        unsigned long long bal = __ballot(m != 0);
        int prefix = __popcll(bal & ((1ull << lane) - 1ull));
        int rank = found + prefix;
        if (m && rank < KP) seed[prob * KP + rank] = base + idx;  // global support point idx
        found += __popcll(bal);
    }
}

// ---------------- kernel 3a: per-tile sim max (assignment partials) ----------------
// grid (160, 5): x = point block (40 fg0, 40 fg1, 80 bg), y = proto tile
__global__ __launch_bounds__(256) void k_assign_partial(const float* __restrict__ sup,
                                                        const float* __restrict__ srn,
                                                        const int* __restrict__ seed,
                                                        float* __restrict__ pmaxv,
                                                        int* __restrict__ pmaxj) {
    __shared__ float sh[C][JT];
    __shared__ int   sseed[JT];
    __shared__ float ssrn[JT];
    int b = blockIdx.x, jt = blockIdx.y, tid = threadIdx.x;
    int prob, p, gbase, aoff;
    if (b < 40)      { prob = 0; p = b * 256 + tid;        gbase = 0;     aoff = 0; }
    else if (b < 80) { prob = 1; p = (b - 40) * 256 + tid; gbase = 10240; aoff = 10240; }
    else             { prob = 2; p = (b - 80) * 256 + tid; gbase = 0;     aoff = 20480; }
    int j0 = jt * JT;
    if (tid < JT) {
        int sp = seed[prob * KP + j0 + tid];
        sseed[tid] = sp;
        ssrn[tid]  = srn[sp];
    }
    __syncthreads();
    for (int i = tid; i < C * JT; i += 256) {
        int jj = i / C, c = i % C;
        int sp = sseed[jj];
        sh[c][jj] = sup[((size_t)(sp >> 11) * C + c) * NPTS + (sp & 2047)] * ssrn[jj];
    }
    __syncthreads();
    int g = gbase + p;
    const float* fb = sup + ((size_t)(g >> 11) * C) * NPTS + (g & 2047);
    float acc[JT];
    #pragma unroll
    for (int j = 0; j < JT; j++) acc[j] = 0.f;
    #pragma unroll 4
    for (int c = 0; c < C; c++) {
        float pv = fb[(size_t)c * NPTS];
        #pragma unroll
        for (int j = 0; j < JT; j++) acc[j] += pv * sh[c][j];
    }
    float bv = acc[0]; int bj = 0;
    #pragma unroll
    for (int j = 1; j < JT; j++) if (acc[j] > bv) { bv = acc[j]; bj = j; }
    int aidx = aoff + p;
    pmaxv[(size_t)aidx * 5 + jt] = bv;
    pmaxj[(size_t)aidx * 5 + jt] = j0 + bj;
}

// ---------------- kernel 3b: combine tiles -> assignment ----------------
__global__ __launch_bounds__(256) void k_assign_combine(const float* __restrict__ pmaxv,
                                                        const int* __restrict__ pmaxj,
                                                        int* __restrict__ assign) {
    int i = blockIdx.x * 256 + threadIdx.x;   // 0..40959
    float bv = pmaxv[(size_t)i * 5]; int bj = pmaxj[(size_t)i * 5];
    #pragma unroll
    for (int t = 1; t < 5; t++) {
        float v = pmaxv[(size_t)i * 5 + t];
        if (v > bv) { bv = v; bj = pmaxj[(size_t)i * 5 + t]; }
    }
    assign[i] = bj;
}

// ---------------- kernel 4: masked cluster accumulation ----------------
__global__ __launch_bounds__(256) void k_accum(const float* __restrict__ sup,
                                               const int* __restrict__ y,
                                               const int* __restrict__ assign,
                                               float* __restrict__ num,
                                               float* __restrict__ den) {
    int b = blockIdx.x, tid = threadIdx.x;
    int prob, p, gbase, aoff, pbase;
    if (b < 40)      { prob = 0; p = b * 256 + tid;        gbase = 0;     aoff = 0;     pbase = 100; }
    else if (b < 80) { prob = 1; p = (b - 40) * 256 + tid; gbase = 10240; aoff = 10240; pbase = 200; }
    else             { prob = 2; p = (b - 80) * 256 + tid; gbase = 0;     aoff = 20480; pbase = 0; }
    int g = gbase + p;
    int yy = y[g];
    int m = (prob == 2) ? (1 - yy) : yy;
    if (!m) return;
    int dst = pbase + assign[aoff + p];
    const float* fb = sup + ((size_t)(g >> 11) * C) * NPTS + (g & 2047);
    atomicAdd(&den[dst], 1.0f);
    float* nb = num + (size_t)dst * C;
    for (int c = 0; c < C; c++) atomicAdd(&nb[c], fb[(size_t)c * NPTS]);
}

// ---------------- kernel 5: finalize + l2-normalize prototypes (in place) ----------------
__global__ __launch_bounds__(64) void k_proto(float* __restrict__ num, const float* __restrict__ den) {
    int pidx = blockIdx.x;     // 0..299
    int tid  = threadIdx.x;    // 64 threads = 1 wave
    float inv = 1.0f / (den[pidx] + 1e-8f);
    float vals[5]; float s = 0.f;
    #pragma unroll
    for (int i = 0; i < 5; i++) {
        float v = num[(size_t)pidx * C + tid + i * 64] * inv;
        vals[i] = v; s += v * v;
    }
    #pragma unroll
    for (int off = 32; off > 0; off >>= 1) s += __shfl_down(s, off);
    s = __shfl(s, 0);
    float rn = 1.0f / (sqrtf(s) + 1e-8f);
    #pragma unroll
    for (int i = 0; i < 5; i++) num[(size_t)pidx * C + tid + i * 64] = vals[i] * rn;
}

// ---------------- kernel 6a: query x proto-tile partial max ----------------
// grid (16, 15)
__global__ __launch_bounds__(256) void k_qpartial(const float* __restrict__ qry,
                                                  const float* __restrict__ phat,
                                                  float* __restrict__ qmaxv) {
    __shared__ float sh[C][JT];
    int pb = blockIdx.x, jt = blockIdx.y, tid = threadIdx.x;
    int j0 = jt * JT;
    for (int i = tid; i < C * JT; i += 256) {
        int jj = i / C, c = i % C;
        sh[c][jj] = phat[(size_t)(j0 + jj) * C + c];
    }
    __syncthreads();
    int m = pb * 256 + tid;
    const float* fb = qry + ((size_t)(m >> 11) * C) * NPTS + (m & 2047);
    float acc[JT];
    #pragma unroll
    for (int j = 0; j < JT; j++) acc[j] = 0.f;
    #pragma unroll 4
    for (int c = 0; c < C; c++) {
        float pv = fb[(size_t)c * NPTS];
        #pragma unroll
        for (int j = 0; j < JT; j++) acc[j] += pv * sh[c][j];
    }
    float bv = acc[0];
    #pragma unroll
    for (int j = 1; j < JT; j++) bv = fmaxf(bv, acc[j]);
    qmaxv[(size_t)m * 15 + jt] = bv;
}

// ---------------- kernel 6b: per-class max, softmax CE, write pred ----------------
__global__ __launch_bounds__(256) void k_pred(const float* __restrict__ qmaxv,
                                              const float* __restrict__ qrn,
                                              const int* __restrict__ qy,
                                              float* __restrict__ out,
                                              float* __restrict__ lossacc) {
    int m = blockIdx.x * 256 + threadIdx.x;  // 0..4095
    float rn = qrn[m];
    float pred[NCLS];
    #pragma unroll
    for (int cls = 0; cls < NCLS; cls++) {
        float g = qmaxv[(size_t)m * 15 + cls * 5];
        #pragma unroll
        for (int t = 1; t < 5; t++) g = fmaxf(g, qmaxv[(size_t)m * 15 + cls * 5 + t]);
        pred[cls] = rn * g;
    }
    int q = m >> 11, n = m & 2047;
    #pragma unroll
    for (int cls = 0; cls < NCLS; cls++)
        out[1 + ((size_t)(q * NCLS + cls)) * NPTS + n] = pred[cls];
    float mx = fmaxf(pred[0], fmaxf(pred[1], pred[2]));
    float lse = mx + logf(expf(pred[0] - mx) + expf(pred[1] - mx) + expf(pred[2] - mx));
    int lab = qy[m];
    atomicAdd(lossacc, lse - pred[lab]);   // = -log p[label]
}

// ---------------- kernel 7: final labels + loss ----------------
__global__ __launch_bounds__(256) void k_final(float* __restrict__ out,
                                               const float* __restrict__ lossacc) {
    __shared__ float red[256];
    const float* pr = out + 1;
    int tid = threadIdx.x;
    float conf[16]; int lab[16];
    float s = 0.f;
    #pragma unroll
    for (int i = 0; i < 16; i++) {
        int m = tid + i * 256;          // 0..4095
        int q = m >> 11, n = m & 2047;
        float p0 = pr[((size_t)(q * NCLS + 0)) * NPTS + n];
        float p1 = pr[((size_t)(q * NCLS + 1)) * NPTS + n];
        float p2 = pr[((size_t)(q * NCLS + 2)) * NPTS + n];
        int l = 0; float c = p0;
        if (p1 > c) { c = p1; l = 1; }
        if (p2 > c) { c = p2; l = 2; }
        conf[i] = c; lab[i] = l; s += c;
    }
    red[tid] = s; __syncthreads();
    for (int off = 128; off > 0; off >>= 1) {
        if (tid < off) red[tid] += red[tid + off];
        __syncthreads();
    }
    float mean = red[0] / (float)QPTS;
    #pragma unroll
    for (int i = 0; i < 16; i++) {
        int m = tid + i * 256;
        out[1 + 2 * NCLS * NPTS + m] = (conf[i] > mean) ? (float)lab[i] : -1.0f;
    }
    if (tid == 0) out[0] = 2.0f * lossacc[0] / (float)QPTS;
}

extern "C" void kernel_launch(void* const* d_in, const int* in_sizes, int n_in,
                              void* d_out, int out_size, void* d_ws, size_t ws_size,
                              hipStream_t stream) {
    const float* sup = (const float*)d_in[0];   // [2,5,320,2048]
    const float* qry = (const float*)d_in[1];   // [2,320,2048]
    const int*   sy  = (const int*)d_in[2];     // [2,5,2048]
    const int*   qy  = (const int*)d_in[3];     // [2,2048]
    float* out = (float*)d_out;

    // workspace layout (floats, then ints)
    float* f      = (float*)d_ws;
    float* srn    = f;                 // 20480
    float* qrn    = srn + SUPPTS;      // 4096
    float* pmaxv  = qrn + QPTS;        // 40960*5 = 204800
    float* qmaxv  = pmaxv + 204800;    // 4096*15 = 61440
    float* num    = qmaxv + 61440;     // 300*320 = 96000
    float* den    = num + 96000;       // 300
    float* loss   = den + 300;         // 1
    int*   seed   = (int*)(loss + 1);  // 300
    int*   assign = seed + 300;        // 40960

    // zero the accumulators (ws is poisoned 0xAA before every launch)
    hipMemsetAsync(num, 0, (96000 + 300 + 1) * sizeof(float), stream);

    k_rnorm<<<96, 256, 0, stream>>>(sup, qry, srn, qrn);
    k_seeds<<<3, 64, 0, stream>>>(sy, seed);
    {
        dim3 grid(160, 5);
        k_assign_partial<<<grid, 256, 0, stream>>>(sup, srn, seed, pmaxv, assign /*unused*/ + 0 == assign ? (int*)(assign + 40960) : (int*)(assign + 40960));
    }
    k_assign_combine<<<160, 256, 0, stream>>>(pmaxv, (int*)(assign + 40960), assign);
    k_accum<<<160, 256, 0, stream>>>(sup, sy, assign, num, den);
    k_proto<<<300, 64, 0, stream>>>(num, den);
    {
        dim3 grid(16, 15);
        k_qpartial<<<grid, 256, 0, stream>>>(qry, num, qmaxv);
    }
    k_pred<<<16, 256, 0, stream>>>(qmaxv, qrn, qy, out, loss);
    k_final<<<1, 256, 0, stream>>>(out, loss);
}

// Round 2
// 265.082 us; speedup vs baseline: 2.9972x; 2.9972x over previous
//
#include <hip/hip_runtime.h>
#include <math.h>

#define C 320
#define NPTS 2048
#define SUPPTS 20480   // 2*5*2048 support points
#define QPTS 4096      // 2*2048 query points
#define KP 100         // prototypes per problem
#define JT 20          // proto tile size
#define NCLS 3

// ---------------- kernel 1: reciprocal norms ----------------
__global__ __launch_bounds__(256) void k_rnorm(const float* __restrict__ sup,
                                               const float* __restrict__ qry,
                                               float* __restrict__ srn,
                                               float* __restrict__ qrn) {
    int i = blockIdx.x * 256 + threadIdx.x;   // 0..24575
    if (i < SUPPTS) {
        int ws = i >> 11, n = i & 2047;
        const float* base = sup + ((size_t)ws * C) * NPTS + n;
        float s = 0.f;
        #pragma unroll 8
        for (int c = 0; c < C; c++) { float v = base[(size_t)c * NPTS]; s += v * v; }
        srn[i] = 1.0f / (sqrtf(s) + 1e-8f);
    } else {
        int j = i - SUPPTS;                   // 0..4095
        int q = j >> 11, n = j & 2047;
        const float* base = qry + ((size_t)q * C) * NPTS + n;
        float s = 0.f;
        #pragma unroll 8
        for (int c = 0; c < C; c++) { float v = base[(size_t)c * NPTS]; s += v * v; }
        qrn[j] = 1.0f / (sqrtf(s) + 1e-8f);
    }
}

// ---------------- kernel 2: seed selection (first 100 masked per problem) ----------------
__global__ __launch_bounds__(64) void k_seeds(const int* __restrict__ y, int* __restrict__ seed) {
    int prob = blockIdx.x;            // 0: fg way0, 1: fg way1, 2: bg (all)
    int lane = threadIdx.x;
    int M    = (prob == 2) ? SUPPTS : 10240;
    int base = (prob == 1) ? 10240 : 0;
    int found = 0;
    for (int chunk = 0; chunk < M && found < KP; chunk += 64) {
        int idx = chunk + lane;
        int yy = y[base + idx];
        int m = (prob == 2) ? (1 - yy) : yy;
        unsigned long long bal = __ballot(m != 0);
        int prefix = __popcll(bal & ((1ull << lane) - 1ull));
        int rank = found + prefix;
        if (m && rank < KP) seed[prob * KP + rank] = base + idx;  // global support point idx
        found += __popcll(bal);
    }
}

// ---------------- kernel 3a: per-tile sim max (assignment partials) ----------------
// grid (160, 5): x = point block (40 fg0, 40 fg1, 80 bg), y = proto tile
__global__ __launch_bounds__(256) void k_assign_partial(const float* __restrict__ sup,
                                                        const float* __restrict__ srn,
                                                        const int* __restrict__ seed,
                                                        float* __restrict__ pmaxv,
                                                        int* __restrict__ pmaxj) {
    __shared__ float sh[C][JT];
    __shared__ int   sseed[JT];
    __shared__ float ssrn[JT];
    int b = blockIdx.x, jt = blockIdx.y, tid = threadIdx.x;
    int prob, p, gbase, aoff;
    if (b < 40)      { prob = 0; p = b * 256 + tid;        gbase = 0;     aoff = 0; }
    else if (b < 80) { prob = 1; p = (b - 40) * 256 + tid; gbase = 10240; aoff = 10240; }
    else             { prob = 2; p = (b - 80) * 256 + tid; gbase = 0;     aoff = 20480; }
    int j0 = jt * JT;
    if (tid < JT) {
        int sp = seed[prob * KP + j0 + tid];
        sseed[tid] = sp;
        ssrn[tid]  = srn[sp];
    }
    __syncthreads();
    for (int i = tid; i < C * JT; i += 256) {
        int jj = i / C, c = i % C;
        int sp = sseed[jj];
        sh[c][jj] = sup[((size_t)(sp >> 11) * C + c) * NPTS + (sp & 2047)] * ssrn[jj];
    }
    __syncthreads();
    int g = gbase + p;
    const float* fb = sup + ((size_t)(g >> 11) * C) * NPTS + (g & 2047);
    float acc[JT];
    #pragma unroll
    for (int j = 0; j < JT; j++) acc[j] = 0.f;
    #pragma unroll 4
    for (int c = 0; c < C; c++) {
        float pv = fb[(size_t)c * NPTS];
        #pragma unroll
        for (int j = 0; j < JT; j++) acc[j] += pv * sh[c][j];
    }
    float bv = acc[0]; int bj = 0;
    #pragma unroll
    for (int j = 1; j < JT; j++) if (acc[j] > bv) { bv = acc[j]; bj = j; }
    int aidx = aoff + p;
    pmaxv[(size_t)aidx * 5 + jt] = bv;
    pmaxj[(size_t)aidx * 5 + jt] = j0 + bj;
}

// ---------------- kernel 3b: combine tiles -> per-point destination bin (0..299) ----------------
// bin 0..99 = bg, 100..199 = fg way0, 200..299 = fg way1
__global__ __launch_bounds__(256) void k_combine_dst(const float* __restrict__ pmaxv,
                                                     const int* __restrict__ pmaxj,
                                                     const int* __restrict__ sy,
                                                     int* __restrict__ dst) {
    int g = blockIdx.x * 256 + threadIdx.x;   // 0..20479
    // fg candidate (partials for fg problem of this point's way live at index g)
    float bvf = pmaxv[(size_t)g * 5]; int bjf = pmaxj[(size_t)g * 5];
    #pragma unroll
    for (int t = 1; t < 5; t++) {
        float v = pmaxv[(size_t)g * 5 + t];
        if (v > bvf) { bvf = v; bjf = pmaxj[(size_t)g * 5 + t]; }
    }
    // bg candidate at index 20480+g
    size_t gb = (size_t)(SUPPTS + g) * 5;
    float bvb = pmaxv[gb]; int bjb = pmaxj[gb];
    #pragma unroll
    for (int t = 1; t < 5; t++) {
        float v = pmaxv[gb + t];
        if (v > bvb) { bvb = v; bjb = pmaxj[gb + t]; }
    }
    int way = (g >= 10240) ? 1 : 0;
    dst[g] = sy[g] ? (100 + way * 100 + bjf) : bjb;
}

// ---------------- kernel 4: LDS-binned accumulation (no global atomics) ----------------
// grid (10 ws-slices, 20 channel-tiles of 16). Each block: 2048 pts x 16 ch -> LDS bins[16][200]
__global__ __launch_bounds__(256) void k_accum_lds(const float* __restrict__ sup,
                                                   const int* __restrict__ dst,
                                                   float* __restrict__ part,
                                                   float* __restrict__ cnt) {
    __shared__ float bins[16 * 200];
    __shared__ unsigned short sdst[2048];
    __shared__ float scnt[200];
    int ws = blockIdx.x;     // 0..9 (way*5 + shot)
    int ct = blockIdx.y;     // 0..19
    int tid = threadIdx.x;
    int w = (ws >= 5) ? 1 : 0;
    for (int i = tid; i < 16 * 200; i += 256) bins[i] = 0.f;
    if (ct == 0) { if (tid < 200) scnt[tid] = 0.f; }
    for (int n = tid; n < 2048; n += 256) {
        int d = dst[ws * 2048 + n];
        int local = (d < 100) ? d : (d - w * 100);   // 0..99 bg, 100..199 this-way fg
        sdst[n] = (unsigned short)local;
    }
    __syncthreads();
    if (ct == 0) {
        for (int n = tid; n < 2048; n += 256) atomicAdd(&scnt[sdst[n]], 1.0f);
    }
    const float* base = sup + ((size_t)ws * C + ct * 16) * NPTS;
    for (int cl = 0; cl < 16; cl++) {
        const float* row = base + (size_t)cl * NPTS;
        #pragma unroll
        for (int sub = 0; sub < 8; sub++) {
            int n = sub * 256 + tid;
            atomicAdd(&bins[cl * 200 + sdst[n]], row[n]);
        }
    }
    __syncthreads();
    float* pout = part + (size_t)(ws * 20 + ct) * 200 * 16;
    for (int i = tid; i < 16 * 200; i += 256) {
        int bin = i >> 4, cl = i & 15;
        pout[i] = bins[cl * 200 + bin];       // coalesced write, layout [bin][cl]
    }
    if (ct == 0) { if (tid < 200) cnt[ws * 200 + tid] = scnt[tid]; }
}

// ---------------- kernel 5: reduce partials -> num/den ----------------
__global__ __launch_bounds__(256) void k_reduce(const float* __restrict__ part,
                                                const float* __restrict__ cnt,
                                                float* __restrict__ num,
                                                float* __restrict__ den) {
    int i = blockIdx.x * 256 + threadIdx.x;  // 0..95999
    if (i >= 300 * C) return;
    int d = i / C, c = i % C;
    int ct = c >> 4, cl = c & 15;
    int local, ws0, nws;
    if (d < 100)      { local = d;             ws0 = 0; nws = 10; }
    else if (d < 200) { local = d;             ws0 = 0; nws = 5;  }  // fg way0, local=100+(d-100)
    else              { local = d - 100;       ws0 = 5; nws = 5;  }  // fg way1
    float s = 0.f;
    for (int k = 0; k < nws; k++)
        s += part[((size_t)((ws0 + k) * 20 + ct) * 200 + local) * 16 + cl];
    num[(size_t)d * C + c] = s;
    if (c == 0) {
        float dn = 0.f;
        for (int k = 0; k < nws; k++) dn += cnt[(ws0 + k) * 200 + local];
        den[d] = dn;
    }
}

// ---------------- kernel 6: finalize + l2-normalize prototypes (in place) ----------------
__global__ __launch_bounds__(64) void k_proto(float* __restrict__ num, const float* __restrict__ den) {
    int pidx = blockIdx.x;     // 0..299
    int tid  = threadIdx.x;    // 64 threads = 1 wave
    float inv = 1.0f / (den[pidx] + 1e-8f);
    float vals[5]; float s = 0.f;
    #pragma unroll
    for (int i = 0; i < 5; i++) {
        float v = num[(size_t)pidx * C + tid + i * 64] * inv;
        vals[i] = v; s += v * v;
    }
    #pragma unroll
    for (int off = 32; off > 0; off >>= 1) s += __shfl_down(s, off);
    s = __shfl(s, 0);
    float rn = 1.0f / (sqrtf(s) + 1e-8f);
    #pragma unroll
    for (int i = 0; i < 5; i++) num[(size_t)pidx * C + tid + i * 64] = vals[i] * rn;
}

// ---------------- kernel 7a: query x proto-tile partial max ----------------
// grid (16, 15)
__global__ __launch_bounds__(256) void k_qpartial(const float* __restrict__ qry,
                                                  const float* __restrict__ phat,
                                                  float* __restrict__ qmaxv) {
    __shared__ float sh[C][JT];
    int pb = blockIdx.x, jt = blockIdx.y, tid = threadIdx.x;
    int j0 = jt * JT;
    for (int i = tid; i < C * JT; i += 256) {
        int jj = i / C, c = i % C;
        sh[c][jj] = phat[(size_t)(j0 + jj) * C + c];
    }
    __syncthreads();
    int m = pb * 256 + tid;
    const float* fb = qry + ((size_t)(m >> 11) * C) * NPTS + (m & 2047);
    float acc[JT];
    #pragma unroll
    for (int j = 0; j < JT; j++) acc[j] = 0.f;
    #pragma unroll 4
    for (int c = 0; c < C; c++) {
        float pv = fb[(size_t)c * NPTS];
        #pragma unroll
        for (int j = 0; j < JT; j++) acc[j] += pv * sh[c][j];
    }
    float bv = acc[0];
    #pragma unroll
    for (int j = 1; j < JT; j++) bv = fmaxf(bv, acc[j]);
    qmaxv[(size_t)m * 15 + jt] = bv;
}

// ---------------- kernel 7b: per-class max, softmax CE, write pred ----------------
__global__ __launch_bounds__(256) void k_pred(const float* __restrict__ qmaxv,
                                              const float* __restrict__ qrn,
                                              const int* __restrict__ qy,
                                              float* __restrict__ out,
                                              float* __restrict__ lossacc) {
    int m = blockIdx.x * 256 + threadIdx.x;  // 0..4095
    float rn = qrn[m];
    float pred[NCLS];
    #pragma unroll
    for (int cls = 0; cls < NCLS; cls++) {
        float g = qmaxv[(size_t)m * 15 + cls * 5];
        #pragma unroll
        for (int t = 1; t < 5; t++) g = fmaxf(g, qmaxv[(size_t)m * 15 + cls * 5 + t]);
        pred[cls] = rn * g;
    }
    int q = m >> 11, n = m & 2047;
    #pragma unroll
    for (int cls = 0; cls < NCLS; cls++)
        out[1 + ((size_t)(q * NCLS + cls)) * NPTS + n] = pred[cls];
    float mx = fmaxf(pred[0], fmaxf(pred[1], pred[2]));
    float lse = mx + logf(expf(pred[0] - mx) + expf(pred[1] - mx) + expf(pred[2] - mx));
    int lab = qy[m];
    atomicAdd(lossacc, lse - pred[lab]);   // = -log p[label]
}

// ---------------- kernel 8: final labels + loss ----------------
__global__ __launch_bounds__(256) void k_final(float* __restrict__ out,
                                               const float* __restrict__ lossacc) {
    __shared__ float red[256];
    const float* pr = out + 1;
    int tid = threadIdx.x;
    float conf[16]; int lab[16];
    float s = 0.f;
    #pragma unroll
    for (int i = 0; i < 16; i++) {
        int m = tid + i * 256;          // 0..4095
        int q = m >> 11, n = m & 2047;
        float p0 = pr[((size_t)(q * NCLS + 0)) * NPTS + n];
        float p1 = pr[((size_t)(q * NCLS + 1)) * NPTS + n];
        float p2 = pr[((size_t)(q * NCLS + 2)) * NPTS + n];
        int l = 0; float c = p0;
        if (p1 > c) { c = p1; l = 1; }
        if (p2 > c) { c = p2; l = 2; }
        conf[i] = c; lab[i] = l; s += c;
    }
    red[tid] = s; __syncthreads();
    for (int off = 128; off > 0; off >>= 1) {
        if (tid < off) red[tid] += red[tid + off];
        __syncthreads();
    }
    float mean = red[0] / (float)QPTS;
    #pragma unroll
    for (int i = 0; i < 16; i++) {
        int m = tid + i * 256;
        out[1 + 2 * NCLS * NPTS + m] = (conf[i] > mean) ? (float)lab[i] : -1.0f;
    }
    if (tid == 0) out[0] = 2.0f * lossacc[0] / (float)QPTS;
}

extern "C" void kernel_launch(void* const* d_in, const int* in_sizes, int n_in,
                              void* d_out, int out_size, void* d_ws, size_t ws_size,
                              hipStream_t stream) {
    const float* sup = (const float*)d_in[0];   // [2,5,320,2048]
    const float* qry = (const float*)d_in[1];   // [2,320,2048]
    const int*   sy  = (const int*)d_in[2];     // [2,5,2048]
    const int*   qy  = (const int*)d_in[3];     // [2,2048]
    float* out = (float*)d_out;

    // workspace layout
    float* f      = (float*)d_ws;
    float* srn    = f;                    // 20480
    float* qrn    = srn + SUPPTS;         // 4096
    float* pmaxv  = qrn + QPTS;           // 40960*5 = 204800
    float* qmaxv  = pmaxv + 204800;       // 4096*15 = 61440
    float* num    = qmaxv + 61440;        // 300*320 = 96000
    float* den    = num + 96000;          // 300
    float* loss   = den + 300;            // 1
    float* part   = loss + 1;             // 200 blocks * 200 bins * 16 ch = 640000
    float* cnt    = part + 640000;        // 10*200 = 2000
    int*   seed   = (int*)(cnt + 2000);   // 300
    int*   dstb   = seed + 300;           // 20480
    int*   pmaxj  = dstb + SUPPTS;        // 204800

    hipMemsetAsync(loss, 0, sizeof(float), stream);

    k_rnorm<<<96, 256, 0, stream>>>(sup, qry, srn, qrn);
    k_seeds<<<3, 64, 0, stream>>>(sy, seed);
    {
        dim3 grid(160, 5);
        k_assign_partial<<<grid, 256, 0, stream>>>(sup, srn, seed, pmaxv, pmaxj);
    }
    k_combine_dst<<<80, 256, 0, stream>>>(pmaxv, pmaxj, sy, dstb);
    {
        dim3 grid(10, 20);
        k_accum_lds<<<grid, 256, 0, stream>>>(sup, dstb, part, cnt);
    }
    k_reduce<<<375, 256, 0, stream>>>(part, cnt, num, den);
    k_proto<<<300, 64, 0, stream>>>(num, den);
    {
        dim3 grid(16, 15);
        k_qpartial<<<grid, 256, 0, stream>>>(qry, num, qmaxv);
    }
    k_pred<<<16, 256, 0, stream>>>(qmaxv, qrn, qy, out, loss);
    k_final<<<1, 256, 0, stream>>>(out, loss);
}